// Round 2
// baseline (209.156 us; speedup 1.0000x reference)
//
#include <hip/hip_runtime.h>

// SSIM loss, fused, LDS-free. Inputs: enhanced, target fp32 [16,3,512,512] -> scalar.
// Each thread: 2-column strip x 16 output rows. Horizontal 7-tap from three
// aligned float4 global loads (L1/L2 absorb neighbor overlap); vertical 7-tap
// via a 7-slot register ring of partial sums, fully unrolled (static indices).

#define IMG 512
#define BAND 16           // output rows per block
#define INROWS 22         // BAND + 6 halo rows
#define NPLANES 48
#define SSIM_C1 1.0e-4f
#define SSIM_C2 9.0e-4f

__device__ __constant__ float c_gw[7] = {
    0.03663284536f, 0.11128076166f, 0.21674531251f, 0.27068216094f,
    0.21674531251f, 0.11128076166f, 0.03663284536f};

__global__ __launch_bounds__(256) void ssim_main(
    const float* __restrict__ X, const float* __restrict__ Y,
    float* __restrict__ partial) {
  const int tid = threadIdx.x;            // 0..255
  const int band = blockIdx.x;            // 0..31 (y-band of 16 rows)
  const int plane = blockIdx.y;           // 0..47
  const float* __restrict__ xp = X + (size_t)plane * IMG * IMG;
  const float* __restrict__ yp = Y + (size_t)plane * IMG * IMG;

  const int c = tid * 2;                  // strip start col (0..510)
  const int par = c & 2;                  // 0 or 2
  const int b0 = c - 4 - par;             // aligned base col (multiple of 4)
  const int row0 = band * BAND - 3;       // first input row (may be <0)

  // Column validity: loads are all-or-nothing (b0 multiple of 4).
  const bool ok0 = (b0 >= 0);
  const bool ok2 = (b0 + 8 <= IMG - 4);   // b0+8 load fully in-bounds
  const bool psel = (par != 0);

  float acc[7][10];                       // vertical partials: slot x (ch*2+px)
  float ssim_acc = 0.f;

  const float g0 = c_gw[0], g1 = c_gw[1], g2 = c_gw[2], g3 = c_gw[3];
  const float gw[7] = {g0, g1, g2, g3, g2, g1, g0};

#pragma unroll
  for (int ir = 0; ir < INROWS; ++ir) {
    const int gy = row0 + ir;
    const bool rowok = (unsigned)gy < (unsigned)IMG;
    const size_t roff = (size_t)gy * IMG + b0;

    float4 x0, x1, x2, y0, y1, y2;
    if (rowok && ok0) x0 = *(const float4*)(xp + roff);
    else x0 = make_float4(0.f, 0.f, 0.f, 0.f);
    if (rowok) x1 = *(const float4*)(xp + roff + 4);
    else x1 = make_float4(0.f, 0.f, 0.f, 0.f);
    if (rowok && ok2) x2 = *(const float4*)(xp + roff + 8);
    else x2 = make_float4(0.f, 0.f, 0.f, 0.f);
    if (rowok && ok0) y0 = *(const float4*)(yp + roff);
    else y0 = make_float4(0.f, 0.f, 0.f, 0.f);
    if (rowok) y1 = *(const float4*)(yp + roff + 4);
    else y1 = make_float4(0.f, 0.f, 0.f, 0.f);
    if (rowok && ok2) y2 = *(const float4*)(yp + roff + 8);
    else y2 = make_float4(0.f, 0.f, 0.f, 0.f);

    const float wx[12] = {x0.x, x0.y, x0.z, x0.w, x1.x, x1.y, x1.z, x1.w,
                          x2.x, x2.y, x2.z, x2.w};
    const float wy[12] = {y0.x, y0.y, y0.z, y0.w, y1.x, y1.y, y1.z, y1.w,
                          y2.x, y2.y, y2.z, y2.w};

    // Select 8 window positions (cols c-3..c+4) per channel, per parity.
    float xs[8], ys[8];
#pragma unroll
    for (int j = 0; j < 8; ++j) {
      xs[j] = psel ? wx[j + 3] : wx[j + 1];
      ys[j] = psel ? wy[j + 3] : wy[j + 1];
    }
    float xxs[8], yys[8], xys[8];
#pragma unroll
    for (int j = 0; j < 8; ++j) {
      xxs[j] = xs[j] * xs[j];
      yys[j] = ys[j] * ys[j];
      xys[j] = xs[j] * ys[j];
    }

    // Horizontal 7-tap, 5 channels x 2 px.
    float h[10];
#pragma unroll
    for (int px = 0; px < 2; ++px) {
      float s1 = 0.f, s2 = 0.f, sxx = 0.f, syy = 0.f, sxy = 0.f;
#pragma unroll
      for (int k = 0; k < 7; ++k) {
        const float g = gw[k];
        s1 += g * xs[px + k];
        s2 += g * ys[px + k];
        sxx += g * xxs[px + k];
        syy += g * yys[px + k];
        sxy += g * xys[px + k];
      }
      h[0 * 2 + px] = s1;
      h[1 * 2 + px] = s2;
      h[2 * 2 + px] = sxx;
      h[3 * 2 + px] = syy;
      h[4 * 2 + px] = sxy;
    }

    // Vertical fold into ring (all guards static after full unroll).
#pragma unroll
    for (int d = 0; d < 7; ++d) {
      if (d <= ir && (ir - d) < BAND) {
        const int s = (ir - d) % 7;
        const float g = gw[d];
        if (d == 0) {
#pragma unroll
          for (int q = 0; q < 10; ++q) acc[s][q] = g * h[q];
        } else {
#pragma unroll
          for (int q = 0; q < 10; ++q) acc[s][q] += g * h[q];
        }
      }
    }

    // Emit completed output row ir-6.
    if (ir >= 6) {
      const int s = (ir - 6) % 7;
#pragma unroll
      for (int px = 0; px < 2; ++px) {
        const float mu1 = acc[s][0 * 2 + px];
        const float mu2 = acc[s][1 * 2 + px];
        const float exx = acc[s][2 * 2 + px];
        const float eyy = acc[s][3 * 2 + px];
        const float exy = acc[s][4 * 2 + px];
        const float mu1sq = mu1 * mu1;
        const float mu2sq = mu2 * mu2;
        const float mu12 = mu1 * mu2;
        const float sig1 = exx - mu1sq;
        const float sig2 = eyy - mu2sq;
        const float sig12 = exy - mu12;
        const float num = (2.f * mu12 + SSIM_C1) * (2.f * sig12 + SSIM_C2);
        const float den =
            (mu1sq + mu2sq + SSIM_C1) * (sig1 + sig2 + SSIM_C2);
        ssim_acc += num * __builtin_amdgcn_rcpf(den);
      }
    }
  }

  // Block reduction: wave shuffle tree then LDS across 4 waves.
#pragma unroll
  for (int off = 32; off > 0; off >>= 1)
    ssim_acc += __shfl_down(ssim_acc, off, 64);
  __shared__ float wsum[4];
  if ((tid & 63) == 0) wsum[tid >> 6] = ssim_acc;
  __syncthreads();
  if (tid == 0) {
    partial[(size_t)blockIdx.y * gridDim.x + blockIdx.x] =
        wsum[0] + wsum[1] + wsum[2] + wsum[3];
  }
}

__global__ __launch_bounds__(256) void ssim_reduce(
    const float* __restrict__ partial, int n, float* __restrict__ out) {
  float acc = 0.f;
  for (int i = threadIdx.x; i < n; i += 256) acc += partial[i];
#pragma unroll
  for (int off = 32; off > 0; off >>= 1) acc += __shfl_down(acc, off, 64);
  __shared__ float wsum[4];
  if ((threadIdx.x & 63) == 0) wsum[threadIdx.x >> 6] = acc;
  __syncthreads();
  if (threadIdx.x == 0) {
    out[0] = 1.f - (wsum[0] + wsum[1] + wsum[2] + wsum[3]) *
                       (1.f / (float)(NPLANES * IMG * IMG));
  }
}

extern "C" void kernel_launch(void* const* d_in, const int* in_sizes, int n_in,
                              void* d_out, int out_size, void* d_ws, size_t ws_size,
                              hipStream_t stream) {
  const float* enhanced = (const float*)d_in[0];
  const float* target = (const float*)d_in[1];
  float* out = (float*)d_out;
  float* partial = (float*)d_ws;

  dim3 grid(IMG / BAND, NPLANES);   // 32 x 48 = 1536 blocks
  ssim_main<<<grid, dim3(256), 0, stream>>>(enhanced, target, partial);

  const int nblocks = (IMG / BAND) * NPLANES;
  ssim_reduce<<<1, 256, 0, stream>>>(partial, nblocks, out);
}